// Round 5
// baseline (139.044 us; speedup 1.0000x reference)
//
#include <hip/hip_runtime.h>
#include <hip/hip_bf16.h>
#include <math.h>

// Problem constants: B=2, C=256, H=W=64 -> HW=4096
#define BB 2
#define CC 256
#define CCP (CC + 2)       // LDS pad: row stride 129 words -> transpose stores 2-way (free)
#define HWN 4096
#define PT 32              // pixels per prep block
#define TM 128             // GEMM block tile (M and N)
#define NBLK (32 * 32 * BB)  // gemm blocks = 2048

typedef __attribute__((ext_vector_type(4))) int   intx4;
typedef __attribute__((ext_vector_type(8))) int   intx8;
typedef __attribute__((ext_vector_type(4))) float floatx4;

__device__ __forceinline__ unsigned short f2bf(float f) {
    union { float f; unsigned u; } v; v.f = f;
    unsigned r = v.u + 0x7FFF + ((v.u >> 16) & 1);   // RNE
    return (unsigned short)(r >> 16);
}

__device__ __forceinline__ float bf2f(unsigned short h) {
    union { unsigned u; float f; } v; v.u = ((unsigned)h) << 16;
    return v.f;
}

// async global->LDS, 16B per lane. LDS dest is wave-uniform base + lane*16.
__device__ __forceinline__ void load_lds16(const void* g, void* l) {
    __builtin_amdgcn_global_load_lds(
        (const __attribute__((address_space(1))) unsigned int*)g,
        (__attribute__((address_space(3))) unsigned int*)l, 16, 0, 0);
}

// One block per (batch, 32-pixel chunk), 1024 threads. float4 global loads
// (4 pixels x 2 channels per thread = 6 vector loads). Writes A=norm(dv),
// D=norm(df)-norm(di) transposed to [b][pixel][channel] fp8-e4m3. Per-block
// kp/desc partials to arrays (no contended global atomics). Block 0 also
// zeroes the gemm done-counter (d_ws is re-poisoned 0xAA before every launch).
__global__ __launch_bounds__(1024) void prep_kernel(
    const float* __restrict__ sv, const float* __restrict__ si,
    const float* __restrict__ sf, const float* __restrict__ dv,
    const float* __restrict__ di, const float* __restrict__ df,
    unsigned char* __restrict__ Af8, unsigned char* __restrict__ Df8,
    float* __restrict__ pk, float* __restrict__ pd,
    unsigned int* __restrict__ cnt)
{
    __shared__ unsigned short lv[PT][CCP];
    __shared__ unsigned short li[PT][CCP];
    __shared__ unsigned short lf[PT][CCP];
    __shared__ float ssq[3][PT];
    __shared__ float inv[3][PT];
    __shared__ float sdesc;

    const int b   = blockIdx.x / (HWN / PT);
    const int p0  = (blockIdx.x % (HWN / PT)) * PT;
    const int tid = threadIdx.x;
    const int tp4 = tid & 7;          // 4-pixel group: pixels 4*tp4..+3
    const int c0  = (tid >> 3) * 2;   // channel pair c0, c0+1

    if (tid < 3 * PT) ((float*)ssq)[tid] = 0.0f;
    if (tid == 0) {
        sdesc = 0.0f;
        if (blockIdx.x == 0) *cnt = 0u;   // reset gemm done-counter
    }
    __syncthreads();

    // Loads: per (channel row, 8 lanes) = 128B contiguous float4 segments.
    const size_t rbase = ((size_t)b * CC + c0) * HWN + p0 + tp4 * 4;
    const floatx4 v0 = *(const floatx4*)(dv + rbase);
    const floatx4 v1 = *(const floatx4*)(dv + rbase + HWN);
    const floatx4 i0 = *(const floatx4*)(di + rbase);
    const floatx4 i1 = *(const floatx4*)(di + rbase + HWN);
    const floatx4 f0 = *(const floatx4*)(df + rbase);
    const floatx4 f1 = *(const floatx4*)(df + rbase + HWN);

    float sqv[4], sqi[4], sqf[4], descp = 0.f;
    #pragma unroll
    for (int k = 0; k < 4; ++k) {
        sqv[k] = v0[k] * v0[k] + v1[k] * v1[k];
        sqi[k] = i0[k] * i0[k] + i1[k] * i1[k];
        sqf[k] = f0[k] * f0[k] + f1[k] * f1[k];
        descp += fabsf(f0[k] - 0.5f * (v0[k] + i0[k]))
               + fabsf(f1[k] - 0.5f * (v1[k] + i1[k]));
        const int p = tp4 * 4 + k;
        // packed bf16 pair -> one ds_write_b32; banks (4*tp4+k+ch2)%32: 2-way
        *(unsigned*)&lv[p][c0] = (unsigned)f2bf(v0[k]) | ((unsigned)f2bf(v1[k]) << 16);
        *(unsigned*)&li[p][c0] = (unsigned)f2bf(i0[k]) | ((unsigned)f2bf(i1[k]) << 16);
        *(unsigned*)&lf[p][c0] = (unsigned)f2bf(f0[k]) | ((unsigned)f2bf(f1[k]) << 16);
    }

    // Reduce squares across the 8 channel-pair lanes sharing a pixel group
    // (lanes l, l+8, ..., l+56), then 12 LDS atomics from lanes 0..7.
    #pragma unroll
    for (int off = 8; off < 64; off <<= 1) {
        #pragma unroll
        for (int k = 0; k < 4; ++k) {
            sqv[k] += __shfl_down(sqv[k], off);
            sqi[k] += __shfl_down(sqi[k], off);
            sqf[k] += __shfl_down(sqf[k], off);
        }
    }
    if ((tid & 63) < 8) {
        #pragma unroll
        for (int k = 0; k < 4; ++k) {
            atomicAdd(&ssq[0][tp4 * 4 + k], sqv[k]);
            atomicAdd(&ssq[1][tp4 * 4 + k], sqi[k]);
            atomicAdd(&ssq[2][tp4 * 4 + k], sqf[k]);
        }
    }

    // desc partial: wave reduce, one LDS atomic per wave
    #pragma unroll
    for (int off = 32; off > 0; off >>= 1) descp += __shfl_down(descp, off);
    if ((tid & 63) == 0) atomicAdd(&sdesc, descp);

    // kp term: this block's 32 pixels (first wave only)
    if (tid < 64) {
        float kpv = 0.f;
        if (tid < PT) {
            const size_t sidx = (size_t)b * HWN + p0 + tid;
            kpv = fabsf(sf[sidx] - fmaxf(sv[sidx], si[sidx]));
        }
        #pragma unroll
        for (int off = 32; off > 0; off >>= 1) kpv += __shfl_down(kpv, off);
        if (tid == 0) pk[blockIdx.x] = kpv;
    }
    __syncthreads();

    if (tid < 3 * PT) {
        const float s = ((float*)ssq)[tid];
        ((float*)inv)[tid] = 1.0f / fmaxf(sqrtf(s), 1e-12f);
    }
    __syncthreads();

    if (tid == 0) pd[blockIdx.x] = sdesc;

    // Write phase: pack 4 channels per int via v_cvt_pk_fp8_f32 (RNE),
    // coalesced dword stores; LDS reads row-contiguous (conflict-free).
    int* Ao = (int*)(Af8 + ((size_t)b * HWN + p0) * CC);
    int* Do = (int*)(Df8 + ((size_t)b * HWN + p0) * CC);
    #pragma unroll
    for (int i = tid; i < PT * CC / 4; i += 1024) {
        const int p = i >> 6, cc0 = (i & 63) * 4;
        const float ia = inv[0][p], ib = inv[1][p], ic = inv[2][p];
        float a0 = bf2f(lv[p][cc0 + 0]) * ia, a1 = bf2f(lv[p][cc0 + 1]) * ia;
        float a2 = bf2f(lv[p][cc0 + 2]) * ia, a3 = bf2f(lv[p][cc0 + 3]) * ia;
        float d0 = bf2f(lf[p][cc0 + 0]) * ic - bf2f(li[p][cc0 + 0]) * ib;
        float d1 = bf2f(lf[p][cc0 + 1]) * ic - bf2f(li[p][cc0 + 1]) * ib;
        float d2 = bf2f(lf[p][cc0 + 2]) * ic - bf2f(li[p][cc0 + 2]) * ib;
        float d3 = bf2f(lf[p][cc0 + 3]) * ic - bf2f(li[p][cc0 + 3]) * ib;
        int wa = __builtin_amdgcn_cvt_pk_fp8_f32(a0, a1, 0, false);
        wa     = __builtin_amdgcn_cvt_pk_fp8_f32(a2, a3, wa, true);
        int wd = __builtin_amdgcn_cvt_pk_fp8_f32(d0, d1, 0, false);
        wd     = __builtin_amdgcn_cvt_pk_fp8_f32(d2, d3, wd, true);
        Ao[i] = wa;
        Do[i] = wd;
    }
}

// Per batch: S = A_rows · D_rows^T, K=256, fp8-e4m3, MX-scaled MFMA
// (16x16x128, unit scales). Whole K staged once into LDS (32KB+32KB),
// single barrier, no K-loop. 4-bit XOR swizzle keeps staging lane-contiguous
// while ds_read_b128 spreads across banks. |.|-sum epilogue -> per-block
// partial; LAST block (device atomic counter) reduces everything -> out.
__global__ __launch_bounds__(256) void gemm_abs_kernel(
    const unsigned char* __restrict__ Af8,
    const unsigned char* __restrict__ Df8,
    float* __restrict__ pg, const float* __restrict__ pk,
    const float* __restrict__ pd, unsigned int* __restrict__ cnt,
    float* __restrict__ out)
{
    __shared__ unsigned char lA[TM * CC];  // 32 KB
    __shared__ unsigned char lB[TM * CC];  // 32 KB
    __shared__ float wsum[4];
    __shared__ int lastflag;

    const int b    = blockIdx.z;
    const int bm   = blockIdx.x * TM;
    const int bn   = blockIdx.y * TM;
    const int tid  = threadIdx.x;
    const int wave = tid >> 6;
    const int lane = tid & 63;
    const int wr   = wave >> 1, wc = wave & 1;

    const unsigned char* Agb = Af8 + (size_t)b * HWN * CC + (size_t)bm * CC;
    const unsigned char* Dgb = Df8 + (size_t)b * HWN * CC + (size_t)bn * CC;

    #pragma unroll
    for (int i = 0; i < 8; ++i) {
        const int r0 = wave * 32 + i * 4;
        const int r  = r0 + (lane >> 4);
        const int cs = (lane & 15) ^ (r & 15);
        const size_t gof = (size_t)r * CC + cs * 16;
        load_lds16(Agb + gof, (char*)lA + r0 * CC);
        load_lds16(Dgb + gof, (char*)lB + r0 * CC);
    }
    __syncthreads();   // vmcnt(0) drain: all staging visible

    floatx4 accf[4][4];
    #pragma unroll
    for (int mi = 0; mi < 4; ++mi)
        #pragma unroll
        for (int ni = 0; ni < 4; ++ni)
            accf[mi][ni] = (floatx4){0.f, 0.f, 0.f, 0.f};

    #pragma unroll
    for (int ks = 0; ks < 2; ++ks) {
        const int cb = ks * 8 + (lane >> 4) * 2;   // logical 16B chunk pair
        intx8 a8[4], b8[4];
        #pragma unroll
        for (int mi = 0; mi < 4; ++mi) {
            const int m = wr * 64 + mi * 16 + (lane & 15);
            const char* pa = (const char*)lA + m * CC;
            intx4 lo = *(const intx4*)(pa + ((cb    ) ^ (m & 15)) * 16);
            intx4 hi = *(const intx4*)(pa + ((cb + 1) ^ (m & 15)) * 16);
            a8[mi] = __builtin_shufflevector(lo, hi, 0, 1, 2, 3, 4, 5, 6, 7);
        }
        #pragma unroll
        for (int ni = 0; ni < 4; ++ni) {
            const int n = wc * 64 + ni * 16 + (lane & 15);
            const char* pb = (const char*)lB + n * CC;
            intx4 lo = *(const intx4*)(pb + ((cb    ) ^ (n & 15)) * 16);
            intx4 hi = *(const intx4*)(pb + ((cb + 1) ^ (n & 15)) * 16);
            b8[ni] = __builtin_shufflevector(lo, hi, 0, 1, 2, 3, 4, 5, 6, 7);
        }
        #pragma unroll
        for (int mi = 0; mi < 4; ++mi)
            #pragma unroll
            for (int ni = 0; ni < 4; ++ni)
                accf[mi][ni] = __builtin_amdgcn_mfma_scale_f32_16x16x128_f8f6f4(
                    a8[mi], b8[ni], accf[mi][ni],
                    0, 0,                      // cbsz=fp8, blgp=fp8
                    0, 0x7F7F7F7F,             // A scales: E8M0 1.0
                    0, 0x7F7F7F7F);            // B scales: E8M0 1.0
    }

    float s = 0.f;
    #pragma unroll
    for (int mi = 0; mi < 4; ++mi)
        #pragma unroll
        for (int ni = 0; ni < 4; ++ni)
            #pragma unroll
            for (int r = 0; r < 4; ++r)
                s += fabsf(accf[mi][ni][r]);
    #pragma unroll
    for (int off = 32; off > 0; off >>= 1) s += __shfl_down(s, off);
    if (lane == 0) wsum[wave] = s;
    __syncthreads();

    const int flat = blockIdx.x + 32 * (blockIdx.y + 32 * blockIdx.z);
    if (tid == 0) {
        pg[flat] = wsum[0] + wsum[1] + wsum[2] + wsum[3];
        __threadfence();                       // release pg[flat]
        const unsigned old = atomicAdd(cnt, 1u);
        lastflag = (old == NBLK - 1) ? 1 : 0;
    }
    __syncthreads();

    if (lastflag) {                            // last block reduces everything
        __threadfence();                       // acquire all pg stores
        float r = 0.f;
        #pragma unroll
        for (int i = 0; i < NBLK / 256; ++i)
            r += pg[tid + i * 256];
        r *= (1.0f / 33554432.0f);             // match / (B*HW*HW)
        r += pk[tid] * (1.0f / 8192.0f)        // kp / (B*HW)
           + pd[tid] * (1.0f / 2097152.0f);    // desc / (B*C*HW)
        #pragma unroll
        for (int off = 32; off > 0; off >>= 1) r += __shfl_down(r, off);
        if (lane == 0) wsum[wave] = r;
        __syncthreads();
        if (tid == 0) out[0] = wsum[0] + wsum[1] + wsum[2] + wsum[3];
    }
}

extern "C" void kernel_launch(void* const* d_in, const int* in_sizes, int n_in,
                              void* d_out, int out_size, void* d_ws, size_t ws_size,
                              hipStream_t stream) {
    const float* sv = (const float*)d_in[0];
    const float* si = (const float*)d_in[1];
    const float* sf = (const float*)d_in[2];
    const float* dv = (const float*)d_in[3];
    const float* di = (const float*)d_in[4];
    const float* df = (const float*)d_in[5];

    unsigned char* Af8 = (unsigned char*)d_ws;                 // 2 MB
    unsigned char* Df8 = Af8 + (size_t)BB * HWN * CC;          // 2 MB
    float* pg = (float*)(Df8 + (size_t)BB * HWN * CC);         // 8 KB (2048)
    float* pk = pg + NBLK;                                     // 1 KB (256)
    float* pd = pk + 256;                                      // 1 KB (256)
    unsigned int* cnt = (unsigned int*)(pd + 256);             // 4 B

    prep_kernel<<<dim3(BB * (HWN / PT)), 1024, 0, stream>>>(
        sv, si, sf, dv, di, df, Af8, Df8, pk, pd, cnt);
    gemm_abs_kernel<<<dim3(HWN / TM, HWN / TM, BB), 256, 0, stream>>>(
        Af8, Df8, pg, pk, pd, cnt, (float*)d_out);
}

// Round 6
// 98.007 us; speedup vs baseline: 1.4187x; 1.4187x over previous
//
#include <hip/hip_runtime.h>
#include <hip/hip_bf16.h>
#include <math.h>

// Problem constants: B=2, C=256, H=W=64 -> HW=4096
#define BB 2
#define CC 256
#define CCP (CC + 2)       // LDS pad for prep transpose stores
#define HWN 4096
#define PT 32              // pixels per prep block
#define NBLK (32 * 32 * BB)  // gemm blocks = 2048

// Fragment-blocked fp8 layout (per batch): for row r (pixel), k-byte kb:
//   addr = (r>>4)*4096 + (kb>>5)*512 + (r&15)*32 + (kb&31)
// => an MFMA fragment load (16 rows x 32 k-bytes, lane L: row L&15,
//    kb (L>>4)*32) is ONE contiguous 2KB wave transaction. No LDS needed.

typedef __attribute__((ext_vector_type(4))) int   intx4;
typedef __attribute__((ext_vector_type(8))) int   intx8;
typedef __attribute__((ext_vector_type(4))) float floatx4;

__device__ __forceinline__ unsigned short f2bf(float f) {
    union { float f; unsigned u; } v; v.f = f;
    unsigned r = v.u + 0x7FFF + ((v.u >> 16) & 1);   // RNE
    return (unsigned short)(r >> 16);
}

__device__ __forceinline__ float bf2f(unsigned short h) {
    union { unsigned u; float f; } v; v.u = ((unsigned)h) << 16;
    return v.f;
}

// One block per (batch, 32-pixel chunk), 1024 threads. float4 global loads.
// Writes A=norm(dv), D=norm(df)-norm(di) in fragment-blocked fp8-e4m3.
// Per-block kp/desc partials to arrays (no contended global atomics).
__global__ __launch_bounds__(1024) void prep_kernel(
    const float* __restrict__ sv, const float* __restrict__ si,
    const float* __restrict__ sf, const float* __restrict__ dv,
    const float* __restrict__ di, const float* __restrict__ df,
    unsigned char* __restrict__ Af8, unsigned char* __restrict__ Df8,
    float* __restrict__ pk, float* __restrict__ pd)
{
    __shared__ unsigned short lv[PT][CCP];
    __shared__ unsigned short li[PT][CCP];
    __shared__ unsigned short lf[PT][CCP];
    __shared__ float ssq[3][PT];
    __shared__ float inv[3][PT];
    __shared__ float sdesc;

    const int b   = blockIdx.x / (HWN / PT);
    const int p0  = (blockIdx.x % (HWN / PT)) * PT;
    const int tid = threadIdx.x;
    const int tp4 = tid & 7;          // 4-pixel group: pixels 4*tp4..+3
    const int c0  = (tid >> 3) * 2;   // channel pair c0, c0+1

    if (tid < 3 * PT) ((float*)ssq)[tid] = 0.0f;
    if (tid == 0) sdesc = 0.0f;
    __syncthreads();

    // Loads: per (channel row, 8 lanes) = 128B contiguous float4 segments.
    const size_t rbase = ((size_t)b * CC + c0) * HWN + p0 + tp4 * 4;
    const floatx4 v0 = *(const floatx4*)(dv + rbase);
    const floatx4 v1 = *(const floatx4*)(dv + rbase + HWN);
    const floatx4 i0 = *(const floatx4*)(di + rbase);
    const floatx4 i1 = *(const floatx4*)(di + rbase + HWN);
    const floatx4 f0 = *(const floatx4*)(df + rbase);
    const floatx4 f1 = *(const floatx4*)(df + rbase + HWN);

    float sqv[4], sqi[4], sqf[4], descp = 0.f;
    #pragma unroll
    for (int k = 0; k < 4; ++k) {
        sqv[k] = v0[k] * v0[k] + v1[k] * v1[k];
        sqi[k] = i0[k] * i0[k] + i1[k] * i1[k];
        sqf[k] = f0[k] * f0[k] + f1[k] * f1[k];
        descp += fabsf(f0[k] - 0.5f * (v0[k] + i0[k]))
               + fabsf(f1[k] - 0.5f * (v1[k] + i1[k]));
        const int p = tp4 * 4 + k;
        *(unsigned*)&lv[p][c0] = (unsigned)f2bf(v0[k]) | ((unsigned)f2bf(v1[k]) << 16);
        *(unsigned*)&li[p][c0] = (unsigned)f2bf(i0[k]) | ((unsigned)f2bf(i1[k]) << 16);
        *(unsigned*)&lf[p][c0] = (unsigned)f2bf(f0[k]) | ((unsigned)f2bf(f1[k]) << 16);
    }

    // Reduce squares across the 8 channel-pair lanes sharing a pixel group.
    #pragma unroll
    for (int off = 8; off < 64; off <<= 1) {
        #pragma unroll
        for (int k = 0; k < 4; ++k) {
            sqv[k] += __shfl_down(sqv[k], off);
            sqi[k] += __shfl_down(sqi[k], off);
            sqf[k] += __shfl_down(sqf[k], off);
        }
    }
    if ((tid & 63) < 8) {
        #pragma unroll
        for (int k = 0; k < 4; ++k) {
            atomicAdd(&ssq[0][tp4 * 4 + k], sqv[k]);
            atomicAdd(&ssq[1][tp4 * 4 + k], sqi[k]);
            atomicAdd(&ssq[2][tp4 * 4 + k], sqf[k]);
        }
    }

    // desc partial: wave reduce, one LDS atomic per wave
    #pragma unroll
    for (int off = 32; off > 0; off >>= 1) descp += __shfl_down(descp, off);
    if ((tid & 63) == 0) atomicAdd(&sdesc, descp);

    // kp term: this block's 32 pixels (first wave only)
    if (tid < 64) {
        float kpv = 0.f;
        if (tid < PT) {
            const size_t sidx = (size_t)b * HWN + p0 + tid;
            kpv = fabsf(sf[sidx] - fmaxf(sv[sidx], si[sidx]));
        }
        #pragma unroll
        for (int off = 32; off > 0; off >>= 1) kpv += __shfl_down(kpv, off);
        if (tid == 0) pk[blockIdx.x] = kpv;
    }
    __syncthreads();

    if (tid < 3 * PT) {
        const float s = ((float*)ssq)[tid];
        ((float*)inv)[tid] = 1.0f / fmaxf(sqrtf(s), 1e-12f);
    }
    __syncthreads();

    if (tid == 0) pd[blockIdx.x] = sdesc;

    // Write phase: pack 4 channels per int (v_cvt_pk_fp8_f32, RNE) into the
    // fragment-blocked layout. int index for (pixel P=p0+p, chans c0..c0+3):
    //   (P>>4)*1024 + (c0>>5)*128 + (P&15)*8 + ((c0&31)>>2)
    int* Ao = (int*)(Af8 + (size_t)b * HWN * CC);
    int* Do = (int*)(Df8 + (size_t)b * HWN * CC);
    #pragma unroll
    for (int i = tid; i < PT * CC / 4; i += 1024) {
        const int p = i >> 6, cc0 = (i & 63) * 4;
        const int P = p0 + p;
        const int oidx = (P >> 4) * 1024 + (cc0 >> 5) * 128 + (P & 15) * 8
                       + ((cc0 & 31) >> 2);
        const float ia = inv[0][p], ib = inv[1][p], ic = inv[2][p];
        float a0 = bf2f(lv[p][cc0 + 0]) * ia, a1 = bf2f(lv[p][cc0 + 1]) * ia;
        float a2 = bf2f(lv[p][cc0 + 2]) * ia, a3 = bf2f(lv[p][cc0 + 3]) * ia;
        float d0 = bf2f(lf[p][cc0 + 0]) * ic - bf2f(li[p][cc0 + 0]) * ib;
        float d1 = bf2f(lf[p][cc0 + 1]) * ic - bf2f(li[p][cc0 + 1]) * ib;
        float d2 = bf2f(lf[p][cc0 + 2]) * ic - bf2f(li[p][cc0 + 2]) * ib;
        float d3 = bf2f(lf[p][cc0 + 3]) * ic - bf2f(li[p][cc0 + 3]) * ib;
        int wa = __builtin_amdgcn_cvt_pk_fp8_f32(a0, a1, 0, false);
        wa     = __builtin_amdgcn_cvt_pk_fp8_f32(a2, a3, wa, true);
        int wd = __builtin_amdgcn_cvt_pk_fp8_f32(d0, d1, 0, false);
        wd     = __builtin_amdgcn_cvt_pk_fp8_f32(d2, d3, wd, true);
        Ao[oidx] = wa;
        Do[oidx] = wd;
    }
}

// No-LDS GEMM: one 64x64 output tile per wave, fragments loaded directly
// from global in 2KB contiguous wave transactions (fragment-blocked layout).
// 4 waves/block arranged 2x2 over 128x128 so A/B fragment lines are shared
// via L1. 32 loads + 32 MFMA per wave, zero barriers, zero atomics.
// |.|-sum epilogue (permutation-invariant) -> per-wave partial store.
__global__ __launch_bounds__(256) void gemm_abs_kernel(
    const unsigned char* __restrict__ Af8,
    const unsigned char* __restrict__ Df8,
    float* __restrict__ pg)
{
    const int b    = blockIdx.z;
    const int tid  = threadIdx.x;
    const int wave = tid >> 6;
    const int lane = tid & 63;
    const int wr   = wave >> 1, wc = wave & 1;
    const int mg0  = blockIdx.x * 8 + wr * 4;   // row-group (of 16) base
    const int ng0  = blockIdx.y * 8 + wc * 4;

    const unsigned char* Ab = Af8 + (size_t)b * HWN * CC;
    const unsigned char* Db = Df8 + (size_t)b * HWN * CC;
    // lane offset inside a fragment's 2KB: kchunk (lane>>4)*512 + row (lane&15)*32
    const int lofs = (lane >> 4) * 512 + (lane & 15) * 32;

    intx4 a[4][2][2], bb[4][2][2];
    #pragma unroll
    for (int mi = 0; mi < 4; ++mi)
        #pragma unroll
        for (int ks = 0; ks < 2; ++ks) {
            const unsigned char* pa = Ab + (size_t)(mg0 + mi) * 4096
                                    + ks * 2048 + lofs;
            a[mi][ks][0] = *(const intx4*)(pa);
            a[mi][ks][1] = *(const intx4*)(pa + 16);
        }
    #pragma unroll
    for (int ni = 0; ni < 4; ++ni)
        #pragma unroll
        for (int ks = 0; ks < 2; ++ks) {
            const unsigned char* pb = Db + (size_t)(ng0 + ni) * 4096
                                    + ks * 2048 + lofs;
            bb[ni][ks][0] = *(const intx4*)(pb);
            bb[ni][ks][1] = *(const intx4*)(pb + 16);
        }

    floatx4 accf[4][4];
    #pragma unroll
    for (int mi = 0; mi < 4; ++mi)
        #pragma unroll
        for (int ni = 0; ni < 4; ++ni)
            accf[mi][ni] = (floatx4){0.f, 0.f, 0.f, 0.f};

    #pragma unroll
    for (int ks = 0; ks < 2; ++ks)
        #pragma unroll
        for (int mi = 0; mi < 4; ++mi) {
            const intx8 a8 = __builtin_shufflevector(
                a[mi][ks][0], a[mi][ks][1], 0, 1, 2, 3, 4, 5, 6, 7);
            #pragma unroll
            for (int ni = 0; ni < 4; ++ni) {
                const intx8 b8 = __builtin_shufflevector(
                    bb[ni][ks][0], bb[ni][ks][1], 0, 1, 2, 3, 4, 5, 6, 7);
                accf[mi][ni] = __builtin_amdgcn_mfma_scale_f32_16x16x128_f8f6f4(
                    a8, b8, accf[mi][ni],
                    0, 0,                      // cbsz=fp8, blgp=fp8
                    0, 0x7F7F7F7F,             // A scales: E8M0 1.0
                    0, 0x7F7F7F7F);            // B scales: E8M0 1.0
            }
        }

    float s = 0.f;
    #pragma unroll
    for (int mi = 0; mi < 4; ++mi)
        #pragma unroll
        for (int ni = 0; ni < 4; ++ni)
            #pragma unroll
            for (int r = 0; r < 4; ++r)
                s += fabsf(accf[mi][ni][r]);
    #pragma unroll
    for (int off = 32; off > 0; off >>= 1) s += __shfl_down(s, off);
    if (lane == 0) {
        const int flat = blockIdx.x + 32 * (blockIdx.y + 32 * blockIdx.z);
        pg[flat * 4 + wave] = s;   // per-wave partial, zero contention
    }
}

// Single block: reduce 8192 match partials + 256 kp + 256 desc partials.
__global__ __launch_bounds__(256) void final_kernel(
    const float* __restrict__ pg, const float* __restrict__ pk,
    const float* __restrict__ pd, float* __restrict__ out)
{
    __shared__ float ws[4];
    const int t = threadIdx.x;
    float s = 0.f;
    #pragma unroll
    for (int i = 0; i < 32; ++i)
        s += pg[t + i * 256];
    s *= (1.0f / 33554432.0f);                 // match / (B*HW*HW)
    s += pk[t] * (1.0f / 8192.0f)              // kp / (B*HW)
       + pd[t] * (1.0f / 2097152.0f);          // desc / (B*C*HW)
    #pragma unroll
    for (int off = 32; off > 0; off >>= 1) s += __shfl_down(s, off);
    if ((t & 63) == 0) ws[t >> 6] = s;
    __syncthreads();
    if (t == 0) out[0] = ws[0] + ws[1] + ws[2] + ws[3];
}

extern "C" void kernel_launch(void* const* d_in, const int* in_sizes, int n_in,
                              void* d_out, int out_size, void* d_ws, size_t ws_size,
                              hipStream_t stream) {
    const float* sv = (const float*)d_in[0];
    const float* si = (const float*)d_in[1];
    const float* sf = (const float*)d_in[2];
    const float* dv = (const float*)d_in[3];
    const float* di = (const float*)d_in[4];
    const float* df = (const float*)d_in[5];

    unsigned char* Af8 = (unsigned char*)d_ws;                 // 2 MB
    unsigned char* Df8 = Af8 + (size_t)BB * HWN * CC;          // 2 MB
    float* pg = (float*)(Df8 + (size_t)BB * HWN * CC);         // 32 KB (8192)
    float* pk = pg + 8192;                                     // 1 KB (256)
    float* pd = pk + 256;                                      // 1 KB (256)

    prep_kernel<<<dim3(BB * (HWN / PT)), 1024, 0, stream>>>(
        sv, si, sf, dv, di, df, Af8, Df8, pk, pd);
    gemm_abs_kernel<<<dim3(HWN / 128, HWN / 128, BB), 256, 0, stream>>>(
        Af8, Df8, pg);
    final_kernel<<<1, 256, 0, stream>>>(pg, pk, pd, (float*)d_out);
}